// Round 4
// baseline (55.000 us; speedup 1.0000x reference)
//
#include <hip/hip_runtime.h>
#include <hip/hip_bf16.h>

typedef __bf16 bf16x8 __attribute__((ext_vector_type(8)));
typedef float  f32x4  __attribute__((ext_vector_type(4)));

static constexpr int NB = 8;     // batch
static constexpr int S  = 2048;  // source rows
static constexpr int T  = 2048;  // target rows
static constexpr int D  = 128;   // feature dim
static constexpr int BT = 256;   // target-tile rows per block
static constexpr int BS = 256;   // source-tile rows per block

// 512 threads = 8 waves. Wave (wt,ws) computes a 64(t) x 128(s) sub-tile.
// Output D[t][s] via mfma(tar_frag, src_frag): lane holds col s = lane&15,
// rows t = (lane>>4)*4 + reg  -> per-lane float4 contiguous along t (out's
// innermost dim) -> nontemporal global_store_dwordx4 (bypass L2 so the
// write stream doesn't evict the L2-resident read panels).
__global__ __launch_bounds__(512, 2)
void cosim256(const float* __restrict__ src, const float* __restrict__ tar,
              const int* __restrict__ mask_s, const int* __restrict__ mask_t,
              float* __restrict__ out)
{
    // raw (un-normalized) bf16 panels, 16B-granule XOR swizzle: slot q at (q ^ (row&7))
    __shared__ uint4 ldsT[BT * 16];   // 64 KB  target panel
    __shared__ uint4 ldsS[BS * 16];   // 64 KB  source panel
    __shared__ float invT[BT];        // 1/||tar row||
    __shared__ float invS[BS];        // 1/||src row||

    // ---- XCD-chunked block swizzle: XCD k owns batch k's full 8x8 tile grid ----
    const int r  = blockIdx.x + 8 * (blockIdx.y + 8 * blockIdx.z);  // physical linear id
    const int l  = (r & 7) * 64 + (r >> 3);                          // bijective remap (512 = 8*64)
    const int tt = l & 7;
    const int ts = (l >> 3) & 7;
    const int b  = l >> 6;

    const int tid = threadIdx.x;

    // ---------------- stage: load f32 row, convert raw->bf16, sumsq ----------------
    {
        const int  row = tid & 255;
        const bool isS = (tid >= 256);
        const float* p = isS ? (src + ((size_t)(b * S + ts * BS + row)) * D)
                             : (tar + ((size_t)(b * T + tt * BT + row)) * D);
        uint4* panel = isS ? ldsS : ldsT;
        float ss = 0.f;
        #pragma unroll
        for (int q = 0; q < 16; ++q) {
            const float4 u0 = ((const float4*)p)[2 * q];
            const float4 u1 = ((const float4*)p)[2 * q + 1];
            ss += u0.x * u0.x + u0.y * u0.y + u0.z * u0.z + u0.w * u0.w
                + u1.x * u1.x + u1.y * u1.y + u1.z * u1.z + u1.w * u1.w;
            bf16x8 t;
            t[0] = (__bf16)u0.x; t[1] = (__bf16)u0.y; t[2] = (__bf16)u0.z; t[3] = (__bf16)u0.w;
            t[4] = (__bf16)u1.x; t[5] = (__bf16)u1.y; t[6] = (__bf16)u1.z; t[7] = (__bf16)u1.w;
            panel[row * 16 + (q ^ (row & 7))] = __builtin_bit_cast(uint4, t);
        }
        (isS ? invS : invT)[row] = 1.0f / fmaxf(sqrtf(ss), 1e-12f);
    }
    __syncthreads();

    // ---------------- MFMA: 128 MFMA per wave ----------------
    const int lane = tid & 63;
    const int w    = tid >> 6;
    const int wt   = w >> 1;      // 0..3  target strip (64 rows)
    const int ws   = w & 1;       // 0..1  source strip (128 rows)
    const int r16  = lane & 15;
    const int kg   = lane >> 4;   // 0..3
    const int swz  = r16 & 7;

    f32x4 acc[4][8] = {};

    #pragma unroll
    for (int ks = 0; ks < 4; ++ks) {           // K = 4 * 32
        bf16x8 at[4], bs[8];
        #pragma unroll
        for (int m = 0; m < 4; ++m) {
            const int rl = wt * 64 + m * 16 + r16;
            at[m] = __builtin_bit_cast(bf16x8, ldsT[rl * 16 + ((ks * 4 + kg) ^ swz)]);
        }
        #pragma unroll
        for (int n = 0; n < 8; ++n) {
            const int rl = ws * 128 + n * 16 + r16;
            bs[n] = __builtin_bit_cast(bf16x8, ldsS[rl * 16 + ((ks * 4 + kg) ^ swz)]);
        }
        #pragma unroll
        for (int m = 0; m < 4; ++m)
            #pragma unroll
            for (int n = 0; n < 8; ++n)
                acc[m][n] = __builtin_amdgcn_mfma_f32_16x16x32_bf16(at[m], bs[n], acc[m][n], 0, 0, 0);
    }

    // ---------------- epilogue: scale by invnorms, ReLU, mask, NT float4 store ----------------
    const int* msS = mask_s + b * S + ts * BS;
    const int* msT = mask_t + b * T + tt * BT;

    #pragma unroll
    for (int m = 0; m < 4; ++m) {
        const int tl = wt * 64 + m * 16 + kg * 4;          // this lane's t base (mult of 4)
        const int4   mt4 = *(const int4*)(msT + tl);
        const float4 it4 = *(const float4*)(&invT[tl]);
        const float g0 = mt4.x ? it4.x : 0.f;
        const float g1 = mt4.y ? it4.y : 0.f;
        const float g2 = mt4.z ? it4.z : 0.f;
        const float g3 = mt4.w ? it4.w : 0.f;
        #pragma unroll
        for (int n = 0; n < 8; ++n) {
            const int sl = ws * 128 + n * 16 + r16;        // this lane's s index
            const float fS = msS[sl] ? invS[sl] : 0.f;
            const f32x4 a = acc[m][n];
            f32x4 o;
            o[0] = fmaxf(a[0], 0.f) * g0 * fS;
            o[1] = fmaxf(a[1], 0.f) * g1 * fS;
            o[2] = fmaxf(a[2], 0.f) * g2 * fS;
            o[3] = fmaxf(a[3], 0.f) * g3 * fS;
            float* po = out + ((size_t)(b * S + ts * BS + sl)) * T + tt * BT + tl;
            __builtin_nontemporal_store(o, (f32x4*)po);
        }
    }
}

extern "C" void kernel_launch(void* const* d_in, const int* in_sizes, int n_in,
                              void* d_out, int out_size, void* d_ws, size_t ws_size,
                              hipStream_t stream) {
    const float* src    = (const float*)d_in[0];
    const float* tar    = (const float*)d_in[1];
    const int*   mask_s = (const int*)d_in[2];
    const int*   mask_t = (const int*)d_in[3];
    float*       out    = (float*)d_out;

    dim3 grid(T / BT, S / BS, NB);   // (8, 8, 8) = 512 blocks
    dim3 block(512);
    hipLaunchKernelGGL(cosim256, grid, block, 0, stream, src, tar, mask_s, mask_t, out);
}

// Round 5
// 49.038 us; speedup vs baseline: 1.1216x; 1.1216x over previous
//
#include <hip/hip_runtime.h>
#include <hip/hip_bf16.h>

typedef __bf16 bf16x8 __attribute__((ext_vector_type(8)));
typedef float  f32x4  __attribute__((ext_vector_type(4)));

static constexpr int NB = 8;     // batch
static constexpr int S  = 2048;  // source rows
static constexpr int T  = 2048;  // target rows
static constexpr int D  = 128;   // feature dim
static constexpr int BT = 256;   // target-tile rows per block
static constexpr int BS = 256;   // source-tile rows per block

// 512 threads = 8 waves. Wave (wt,ws) computes a 64(t) x 128(s) sub-tile.
// Epilogue routes finalized values through LDS (panel buffers are dead after
// the K-loop) so global stores are one fully-contiguous 1KB row per wave
// instruction (full 128B lines -> fill-kernel-like write efficiency).
__global__ __launch_bounds__(512, 2)
void cosim256(const float* __restrict__ src, const float* __restrict__ tar,
              const int* __restrict__ mask_s, const int* __restrict__ mask_t,
              float* __restrict__ out)
{
    // raw (un-normalized) bf16 panels, 16B-granule XOR swizzle: slot q at (q ^ (row&7))
    __shared__ uint4 ldsT[BT * 16];   // 64 KB  target panel / epilogue chunk buf 0
    __shared__ uint4 ldsS[BS * 16];   // 64 KB  source panel / epilogue chunk buf 1
    __shared__ float invT[BT];        // 1/||tar row||
    __shared__ float invS[BS];        // 1/||src row||

    // ---- XCD-chunked block swizzle: XCD k owns batch k's full 8x8 tile grid ----
    const int r  = blockIdx.x + 8 * (blockIdx.y + 8 * blockIdx.z);  // physical linear id
    const int l  = (r & 7) * 64 + (r >> 3);                          // bijective remap (512 = 8*64)
    const int tt = l & 7;
    const int ts = (l >> 3) & 7;
    const int b  = l >> 6;

    const int tid = threadIdx.x;

    // ---------------- stage: load f32 row, convert raw->bf16, sumsq ----------------
    {
        const int  row = tid & 255;
        const bool isS = (tid >= 256);
        const float* p = isS ? (src + ((size_t)(b * S + ts * BS + row)) * D)
                             : (tar + ((size_t)(b * T + tt * BT + row)) * D);
        uint4* panel = isS ? ldsS : ldsT;
        float ss = 0.f;
        #pragma unroll
        for (int q = 0; q < 16; ++q) {
            const float4 u0 = ((const float4*)p)[2 * q];
            const float4 u1 = ((const float4*)p)[2 * q + 1];
            ss += u0.x * u0.x + u0.y * u0.y + u0.z * u0.z + u0.w * u0.w
                + u1.x * u1.x + u1.y * u1.y + u1.z * u1.z + u1.w * u1.w;
            bf16x8 t;
            t[0] = (__bf16)u0.x; t[1] = (__bf16)u0.y; t[2] = (__bf16)u0.z; t[3] = (__bf16)u0.w;
            t[4] = (__bf16)u1.x; t[5] = (__bf16)u1.y; t[6] = (__bf16)u1.z; t[7] = (__bf16)u1.w;
            panel[row * 16 + (q ^ (row & 7))] = __builtin_bit_cast(uint4, t);
        }
        (isS ? invS : invT)[row] = 1.0f / fmaxf(sqrtf(ss), 1e-12f);
    }
    __syncthreads();

    // ---------------- MFMA: 128 MFMA per wave ----------------
    const int lane = tid & 63;
    const int w    = tid >> 6;
    const int wt   = w >> 1;      // 0..3  target strip (64 rows)
    const int ws   = w & 1;       // 0..1  source strip (128 rows)
    const int r16  = lane & 15;
    const int kg   = lane >> 4;   // 0..3
    const int swz  = r16 & 7;

    f32x4 acc[4][8] = {};

    #pragma unroll
    for (int ks = 0; ks < 4; ++ks) {           // K = 4 * 32
        bf16x8 at[4], bs[8];
        #pragma unroll
        for (int m = 0; m < 4; ++m) {
            const int rl = wt * 64 + m * 16 + r16;
            at[m] = __builtin_bit_cast(bf16x8, ldsT[rl * 16 + ((ks * 4 + kg) ^ swz)]);
        }
        #pragma unroll
        for (int n = 0; n < 8; ++n) {
            const int rl = ws * 128 + n * 16 + r16;
            bs[n] = __builtin_bit_cast(bf16x8, ldsS[rl * 16 + ((ks * 4 + kg) ^ swz)]);
        }
        #pragma unroll
        for (int m = 0; m < 4; ++m)
            #pragma unroll
            for (int n = 0; n < 8; ++n)
                acc[m][n] = __builtin_amdgcn_mfma_f32_16x16x32_bf16(at[m], bs[n], acc[m][n], 0, 0, 0);
    }

    // ---------------- finalize in regs: ReLU, invnorm scales, mask gates ----------------
    const int* msS = mask_s + b * S + ts * BS;
    const int* msT = mask_t + b * T + tt * BT;

    #pragma unroll
    for (int m = 0; m < 4; ++m) {
        const int tl = wt * 64 + m * 16 + kg * 4;          // this lane's t base (mult of 4)
        const int4   mt4 = *(const int4*)(msT + tl);
        const float4 it4 = *(const float4*)(&invT[tl]);
        const float g0 = mt4.x ? it4.x : 0.f;
        const float g1 = mt4.y ? it4.y : 0.f;
        const float g2 = mt4.z ? it4.z : 0.f;
        const float g3 = mt4.w ? it4.w : 0.f;
        #pragma unroll
        for (int n = 0; n < 8; ++n) {
            const int sl = ws * 128 + n * 16 + r16;        // this lane's s index
            const float fS = msS[sl] ? invS[sl] : 0.f;
            f32x4 a = acc[m][n];
            a[0] = fmaxf(a[0], 0.f) * g0 * fS;
            a[1] = fmaxf(a[1], 0.f) * g1 * fS;
            a[2] = fmaxf(a[2], 0.f) * g2 * fS;
            a[3] = fmaxf(a[3], 0.f) * g3 * fS;
            acc[m][n] = a;
        }
    }

    // ---------------- epilogue: LDS transpose -> fully-coalesced 1KB row stores ----
    // p=0 handles s-chunks {0,128}; p=1 handles {64,192}. ws=0 waves fill ldsT
    // (s in [p*64, p*64+64)), ws=1 waves fill ldsS (s in [128+p*64, ...+64)).
    // Chunk buffer layout: uint4 buf[64 rows][64 slots], slot j stored at j^(row&15).
    uint4* ob = ws ? ldsS : ldsT;
    #pragma unroll
    for (int p = 0; p < 2; ++p) {
        __syncthreads();   // prior phase's LDS reads (MFMA / store-phase) complete
        #pragma unroll
        for (int m = 0; m < 4; ++m) {
            const int j = wt * 16 + m * 4 + kg;            // t-slot (float4 index) 0..63
            #pragma unroll
            for (int q = 0; q < 4; ++q) {
                const int n    = p * 4 + q;
                const int srow = n * 16 + r16 - p * 64;    // 0..63 chunk-local s row
                ob[srow * 64 + (j ^ (srow & 15))] = __builtin_bit_cast(uint4, acc[m][n]);
            }
        }
        __syncthreads();
        // cooperative store: 128 rows (2 chunks), one 1KB row per wave-instruction
        #pragma unroll
        for (int it = 0; it < 16; ++it) {
            const int flat = it * 512 + tid;               // 0..8191
            const int vr   = flat >> 6;                    // 0..127 virtual row
            const int sl4  = flat & 63;                    // float4 slot in row
            const int row  = vr & 63;
            const uint4 v  = (vr < 64 ? ldsT : ldsS)[row * 64 + (sl4 ^ (row & 15))];
            const int s_tile = (vr < 64 ? 0 : 128) + p * 64 + row;
            float* po = out + ((size_t)(b * S + ts * BS + s_tile)) * T + tt * BT + sl4 * 4;
            *(f32x4*)po = __builtin_bit_cast(f32x4, v);
        }
    }
}

extern "C" void kernel_launch(void* const* d_in, const int* in_sizes, int n_in,
                              void* d_out, int out_size, void* d_ws, size_t ws_size,
                              hipStream_t stream) {
    const float* src    = (const float*)d_in[0];
    const float* tar    = (const float*)d_in[1];
    const int*   mask_s = (const int*)d_in[2];
    const int*   mask_t = (const int*)d_in[3];
    float*       out    = (float*)d_out;

    dim3 grid(T / BT, S / BS, NB);   // (8, 8, 8) = 512 blocks
    dim3 block(512);
    hipLaunchKernelGGL(cosim256, grid, block, 0, stream, src, tar, mask_s, mask_t, out);
}

// Round 6
// 41.729 us; speedup vs baseline: 1.3180x; 1.1752x over previous
//
#include <hip/hip_runtime.h>
#include <hip/hip_bf16.h>

typedef __bf16 bf16x8 __attribute__((ext_vector_type(8)));
typedef float  f32x4  __attribute__((ext_vector_type(4)));

static constexpr int NB = 8;
static constexpr int S  = 2048;
static constexpr int T  = 2048;
static constexpr int D  = 128;

// ws layout: wsrc[16384 rows][16 uint4], wtar[16384 rows][16 uint4]  (8 MB)
// Each row: 128 bf16 (normalized, mask-folded), slot q stored at (q ^ (row&7))
// == the exact LDS image the GEMM wants (global_load_lds copies linearly).

__device__ __forceinline__ void g2l(const uint4* g, uint4* l) {
    __builtin_amdgcn_global_load_lds((const __attribute__((address_space(1))) void*)g,
                                     (__attribute__((address_space(3))) void*)l, 16, 0, 0);
}

// ---------------- pass 1: normalize + mask-zero + bf16 + swizzled image ----------------
__global__ __launch_bounds__(512, 2)
void prep(const float* __restrict__ src, const float* __restrict__ tar,
          const int* __restrict__ ms, const int* __restrict__ mt,
          uint4* __restrict__ ws)
{
    const int tid  = threadIdx.x;
    const int row  = blockIdx.x * 256 + (tid >> 1);   // 0..32767
    const int h    = tid & 1;
    const bool isT = row >= NB * S;
    const int  r   = isT ? row - NB * S : row;        // b*2048 + idx
    const float* p = (isT ? tar : src) + (size_t)r * D + h * 64;
    const int   mk = (isT ? mt : ms)[r];
    uint4*      wp = ws + ((size_t)(isT ? NB * S : 0) + r) * 16;

    float4 v[16];
    float ss = 0.f;
    #pragma unroll
    for (int j = 0; j < 16; ++j) {
        v[j] = ((const float4*)p)[j];
        ss += v[j].x * v[j].x + v[j].y * v[j].y + v[j].z * v[j].z + v[j].w * v[j].w;
    }
    ss += __shfl_xor(ss, 1);                          // full-row sumsq (lane pair)
    const float sc = mk ? (1.0f / fmaxf(sqrtf(ss), 1e-12f)) : 0.0f;

    #pragma unroll
    for (int i = 0; i < 8; ++i) {
        const float4 u0 = v[2 * i], u1 = v[2 * i + 1];
        bf16x8 t;
        t[0] = (__bf16)(u0.x * sc); t[1] = (__bf16)(u0.y * sc);
        t[2] = (__bf16)(u0.z * sc); t[3] = (__bf16)(u0.w * sc);
        t[4] = (__bf16)(u1.x * sc); t[5] = (__bf16)(u1.y * sc);
        t[6] = (__bf16)(u1.z * sc); t[7] = (__bf16)(u1.w * sc);
        wp[(h * 8 + i) ^ (r & 7)] = __builtin_bit_cast(uint4, t);
    }
}

// ---------------- pass 2: tiled GEMM, 2 tiles per block, pipelined stores ----------------
__global__ __launch_bounds__(512, 2)
void gemm(const uint4* __restrict__ ws, float* __restrict__ out)
{
    __shared__ uint4 ldsS[256 * 16];   // src panel (B operand, 256 s-rows)
    __shared__ uint4 ldsT[256 * 16];   // tar panel (A operand, 256 t-rows)

    const uint4* wsrc = ws;
    const uint4* wtar = ws + (size_t)NB * S * 16;

    const int p   = blockIdx.x;        // 0..255 ; round-robin => b == XCD id
    const int b   = p & 7;
    const int k   = p >> 3;            // 0..31
    const int ts  = k >> 2;            // 0..7
    const int tt0 = (k & 3) * 2;       // {0,2,4,6}

    const int tid  = threadIdx.x;
    const int lane = tid & 63;
    const int w    = tid >> 6;
    const int wt   = w >> 1;           // 0..3  t-strip (64 rows)
    const int wsp  = w & 1;            // 0..1  s-strip (128 rows)
    const int r16  = lane & 15;
    const int kg   = lane >> 4;        // 0..3
    const int swz  = r16 & 7;

    const uint4* gs  = wsrc + ((size_t)(b * S + ts * 256)) * 16;
    const uint4* gt0 = wtar + ((size_t)(b * T + tt0 * 256)) * 16;
    const uint4* gt1 = gt0 + 256 * 16;

    // stage 1: both panels (linear copy of pre-swizzled image)
    #pragma unroll
    for (int i = 0; i < 8; ++i) {
        const int idx = i * 512 + tid;
        g2l(gs + idx,  &ldsS[i * 512 + w * 64]);
        g2l(gt0 + idx, &ldsT[i * 512 + w * 64]);
    }
    __syncthreads();

    f32x4 acc[4][8];

    #pragma unroll
    for (int tile = 0; tile < 2; ++tile) {
        #pragma unroll
        for (int m = 0; m < 4; ++m)
            #pragma unroll
            for (int n = 0; n < 8; ++n)
                acc[m][n] = f32x4{0.f, 0.f, 0.f, 0.f};

        #pragma unroll
        for (int ks = 0; ks < 4; ++ks) {          // K = 4 * 32
            bf16x8 at[4], bs[8];
            #pragma unroll
            for (int m = 0; m < 4; ++m) {
                const int rl = wt * 64 + m * 16 + r16;
                at[m] = __builtin_bit_cast(bf16x8, ldsT[rl * 16 + ((ks * 4 + kg) ^ swz)]);
            }
            #pragma unroll
            for (int n = 0; n < 8; ++n) {
                const int rl = wsp * 128 + n * 16 + r16;
                bs[n] = __builtin_bit_cast(bf16x8, ldsS[rl * 16 + ((ks * 4 + kg) ^ swz)]);
            }
            #pragma unroll
            for (int m = 0; m < 4; ++m)
                #pragma unroll
                for (int n = 0; n < 8; ++n)
                    acc[m][n] = __builtin_amdgcn_mfma_f32_16x16x32_bf16(at[m], bs[n], acc[m][n], 0, 0, 0);
        }

        if (tile == 0) {
            // all waves done reading ldsT (cheap: no vmem outstanding here)
            __syncthreads();
            // issue next tar panel BEFORE the stores (vmcnt order matters)
            #pragma unroll
            for (int i = 0; i < 8; ++i)
                g2l(gt1 + i * 512 + tid, &ldsT[i * 512 + w * 64]);
            asm volatile("" ::: "memory");        // pin: loads issued before stores
        }

        // epilogue: ReLU + store (norms & masks already folded in prep)
        const int ttc = (tile == 0) ? tt0 : tt0 + 1;
        #pragma unroll
        for (int m = 0; m < 4; ++m) {
            const int tl = wt * 64 + m * 16 + kg * 4;
            #pragma unroll
            for (int n = 0; n < 8; ++n) {
                const int sl = wsp * 128 + n * 16 + r16;
                const f32x4 a = acc[m][n];
                f32x4 o;
                o[0] = fmaxf(a[0], 0.f);
                o[1] = fmaxf(a[1], 0.f);
                o[2] = fmaxf(a[2], 0.f);
                o[3] = fmaxf(a[3], 0.f);
                float* po = out + ((size_t)(b * S + ts * 256 + sl)) * T + ttc * 256 + tl;
                *(f32x4*)po = o;
            }
        }

        if (tile == 0) {
            // wait only the 8 stage loads (32 stores may stay in flight)
            asm volatile("s_waitcnt vmcnt(32)" ::: "memory");
            __builtin_amdgcn_s_barrier();
            __builtin_amdgcn_sched_barrier(0);
        }
    }
}

extern "C" void kernel_launch(void* const* d_in, const int* in_sizes, int n_in,
                              void* d_out, int out_size, void* d_ws, size_t ws_size,
                              hipStream_t stream) {
    const float* src    = (const float*)d_in[0];
    const float* tar    = (const float*)d_in[1];
    const int*   mask_s = (const int*)d_in[2];
    const int*   mask_t = (const int*)d_in[3];
    float*       out    = (float*)d_out;
    uint4*       ws     = (uint4*)d_ws;

    hipLaunchKernelGGL(prep, dim3(128), dim3(512), 0, stream, src, tar, mask_s, mask_t, ws);
    hipLaunchKernelGGL(gemm, dim3(256), dim3(512), 0, stream, ws, out);
}

// Round 7
// 38.934 us; speedup vs baseline: 1.4126x; 1.0718x over previous
//
#include <hip/hip_runtime.h>
#include <hip/hip_bf16.h>

typedef __bf16 bf16x8 __attribute__((ext_vector_type(8)));
typedef float  f32x4  __attribute__((ext_vector_type(4)));

static constexpr int NB = 8;
static constexpr int S  = 2048;
static constexpr int T  = 2048;
static constexpr int D  = 128;

// ws layout: wsrc[16384 rows][16 uint4], wtar[16384 rows][16 uint4]  (8 MB)
// Each row: 128 bf16 (normalized, mask-folded), slot q stored at (q ^ (row&7))
// == the exact LDS image the GEMM wants (global_load_lds copies linearly).

__device__ __forceinline__ void g2l(const uint4* g, uint4* l) {
    __builtin_amdgcn_global_load_lds((const __attribute__((address_space(1))) void*)g,
                                     (__attribute__((address_space(3))) void*)l, 16, 0, 0);
}

// ---------------- pass 1: normalize + mask-zero + bf16 + swizzled image ----------------
// Full chip: 256 blocks x 512 threads, 4 threads per row (32 floats each).
__global__ __launch_bounds__(512, 2)
void prep(const float* __restrict__ src, const float* __restrict__ tar,
          const int* __restrict__ ms, const int* __restrict__ mt,
          uint4* __restrict__ ws)
{
    const int tid  = threadIdx.x;
    const int qid  = blockIdx.x * 512 + tid;    // quarter-row id, 0..131071
    const int row  = qid >> 2;                  // 0..32767  (src rows then tar rows)
    const int q    = qid & 3;
    const bool isT = row >= NB * S;
    const int  r   = isT ? row - NB * S : row;  // 0..16383 within src/tar
    const float* p = (isT ? tar : src) + (size_t)r * D + q * 32;
    const int   mk = (isT ? mt : ms)[r];
    uint4*      wp = ws + (size_t)row * 16;

    float4 v[8];
    float ss = 0.f;
    if (mk) {
        #pragma unroll
        for (int j = 0; j < 8; ++j) {
            v[j] = ((const float4*)p)[j];
            ss += v[j].x * v[j].x + v[j].y * v[j].y + v[j].z * v[j].z + v[j].w * v[j].w;
        }
    } else {
        #pragma unroll
        for (int j = 0; j < 8; ++j) v[j] = float4{0.f, 0.f, 0.f, 0.f};
    }
    ss += __shfl_xor(ss, 1);                    // 4-lane group reduce (lanes of one row)
    ss += __shfl_xor(ss, 2);
    const float sc = mk ? (1.0f / fmaxf(sqrtf(ss), 1e-12f)) : 0.0f;

    #pragma unroll
    for (int i = 0; i < 4; ++i) {
        const float4 u0 = v[2 * i], u1 = v[2 * i + 1];
        bf16x8 t;
        t[0] = (__bf16)(u0.x * sc); t[1] = (__bf16)(u0.y * sc);
        t[2] = (__bf16)(u0.z * sc); t[3] = (__bf16)(u0.w * sc);
        t[4] = (__bf16)(u1.x * sc); t[5] = (__bf16)(u1.y * sc);
        t[6] = (__bf16)(u1.z * sc); t[7] = (__bf16)(u1.w * sc);
        wp[(q * 4 + i) ^ (r & 7)] = __builtin_bit_cast(uint4, t);
    }
}

// ---------------- pass 2: tiled GEMM, 2 tiles per block, pipelined stores ----------------
__global__ __launch_bounds__(512, 2)
void gemm(const uint4* __restrict__ ws, float* __restrict__ out)
{
    __shared__ uint4 ldsS[256 * 16];   // src panel (B operand, 256 s-rows)
    __shared__ uint4 ldsT[256 * 16];   // tar panel (A operand, 256 t-rows)

    const uint4* wsrc = ws;
    const uint4* wtar = ws + (size_t)NB * S * 16;

    const int p   = blockIdx.x;        // 0..255 ; round-robin => b == XCD id
    const int b   = p & 7;
    const int k   = p >> 3;            // 0..31
    const int ts  = k >> 2;            // 0..7
    const int tt0 = (k & 3) * 2;       // {0,2,4,6}

    const int tid  = threadIdx.x;
    const int lane = tid & 63;
    const int w    = tid >> 6;
    const int wt   = w >> 1;           // 0..3  t-strip (64 rows)
    const int wsp  = w & 1;            // 0..1  s-strip (128 rows)
    const int r16  = lane & 15;
    const int kg   = lane >> 4;        // 0..3
    const int swz  = r16 & 7;

    const uint4* gs  = wsrc + ((size_t)(b * S + ts * 256)) * 16;
    const uint4* gt0 = wtar + ((size_t)(b * T + tt0 * 256)) * 16;
    const uint4* gt1 = gt0 + 256 * 16;

    // stage 1: both panels (linear copy of pre-swizzled image)
    #pragma unroll
    for (int i = 0; i < 8; ++i) {
        const int idx = i * 512 + tid;
        g2l(gs + idx,  &ldsS[i * 512 + w * 64]);
        g2l(gt0 + idx, &ldsT[i * 512 + w * 64]);
    }
    __syncthreads();

    f32x4 acc[4][8];

    #pragma unroll
    for (int tile = 0; tile < 2; ++tile) {
        #pragma unroll
        for (int m = 0; m < 4; ++m)
            #pragma unroll
            for (int n = 0; n < 8; ++n)
                acc[m][n] = f32x4{0.f, 0.f, 0.f, 0.f};

        #pragma unroll
        for (int ks = 0; ks < 4; ++ks) {          // K = 4 * 32
            bf16x8 at[4], bs[8];
            #pragma unroll
            for (int m = 0; m < 4; ++m) {
                const int rl = wt * 64 + m * 16 + r16;
                at[m] = __builtin_bit_cast(bf16x8, ldsT[rl * 16 + ((ks * 4 + kg) ^ swz)]);
            }
            #pragma unroll
            for (int n = 0; n < 8; ++n) {
                const int rl = wsp * 128 + n * 16 + r16;
                bs[n] = __builtin_bit_cast(bf16x8, ldsS[rl * 16 + ((ks * 4 + kg) ^ swz)]);
            }
            #pragma unroll
            for (int m = 0; m < 4; ++m)
                #pragma unroll
                for (int n = 0; n < 8; ++n)
                    acc[m][n] = __builtin_amdgcn_mfma_f32_16x16x32_bf16(at[m], bs[n], acc[m][n], 0, 0, 0);
        }

        if (tile == 0) {
            // all waves done reading ldsT (cheap: no vmem outstanding here)
            __syncthreads();
            // issue next tar panel BEFORE the stores (vmcnt order matters)
            #pragma unroll
            for (int i = 0; i < 8; ++i)
                g2l(gt1 + i * 512 + tid, &ldsT[i * 512 + w * 64]);
            asm volatile("" ::: "memory");        // pin: loads issued before stores
        }

        // epilogue: ReLU + store (norms & masks already folded in prep)
        const int ttc = (tile == 0) ? tt0 : tt0 + 1;
        #pragma unroll
        for (int m = 0; m < 4; ++m) {
            const int tl = wt * 64 + m * 16 + kg * 4;
            #pragma unroll
            for (int n = 0; n < 8; ++n) {
                const int sl = wsp * 128 + n * 16 + r16;
                const f32x4 a = acc[m][n];
                f32x4 o;
                o[0] = fmaxf(a[0], 0.f);
                o[1] = fmaxf(a[1], 0.f);
                o[2] = fmaxf(a[2], 0.f);
                o[3] = fmaxf(a[3], 0.f);
                float* po = out + ((size_t)(b * S + ts * 256 + sl)) * T + ttc * 256 + tl;
                *(f32x4*)po = o;
            }
        }

        if (tile == 0) {
            // wait only the 8 stage loads (32 stores may stay in flight)
            asm volatile("s_waitcnt vmcnt(32)" ::: "memory");
            __builtin_amdgcn_s_barrier();
            __builtin_amdgcn_sched_barrier(0);
        }
    }
}

extern "C" void kernel_launch(void* const* d_in, const int* in_sizes, int n_in,
                              void* d_out, int out_size, void* d_ws, size_t ws_size,
                              hipStream_t stream) {
    const float* src    = (const float*)d_in[0];
    const float* tar    = (const float*)d_in[1];
    const int*   mask_s = (const int*)d_in[2];
    const int*   mask_t = (const int*)d_in[3];
    float*       out    = (float*)d_out;
    uint4*       ws     = (uint4*)d_ws;

    hipLaunchKernelGGL(prep, dim3(256), dim3(512), 0, stream, src, tar, mask_s, mask_t, ws);
    hipLaunchKernelGGL(gemm, dim3(256), dim3(512), 0, stream, ws, out);
}